// Round 1
// baseline (6179.998 us; speedup 1.0000x reference)
//
#include <hip/hip_runtime.h>
#include <math.h>

#define NPTS 65536
#define KNN  10
#define PK   25
#define NCOUT 64
#define GRIDB 10
#define NSEG 1000
#define TILE 256

// Workspace layout (floats):
//  [0, NSEG)                    : per-voxel point counts
//  [NSEG, NSEG*4)               : per-voxel sum of point coords [NSEG][3]
//  [NSEG*4, NSEG*4 + NSEG*PK)   : per-voxel sum of influence    [NSEG][PK]
#define WS_FLOATS (NSEG * (1 + 3 + PK))

__global__ __launch_bounds__(256) void knn_kpconv_pool(
    const float* __restrict__ pts,   // [NPTS][3]
    const float* __restrict__ kern,  // [PK][3]
    float* __restrict__ ws)
{
    __shared__ float4 tile[TILE];
    __shared__ float4 kpt[PK];

    const int tid = threadIdx.x;
    const int gid = blockIdx.x * blockDim.x + tid;

    if (tid < PK) {
        kpt[tid] = make_float4(kern[tid*3+0], kern[tid*3+1], kern[tid*3+2], 0.f);
    }

    const float qx = pts[gid*3+0];
    const float qy = pts[gid*3+1];
    const float qz = pts[gid*3+2];

    // top-KNN kept sorted ascending; all indices static (registers, no scratch)
    float knnd[KNN];
    int   knni[KNN];
#pragma unroll
    for (int u = 0; u < KNN; ++u) { knnd[u] = 3.4e38f; knni[u] = 0; }

    for (int t = 0; t < NPTS / TILE; ++t) {
        __syncthreads();
        const float* sp = pts + (t * TILE + tid) * 3;
        tile[tid] = make_float4(sp[0], sp[1], sp[2], 0.f);
        __syncthreads();

#pragma unroll 8
        for (int j = 0; j < TILE; ++j) {
            float4 s = tile[j];               // broadcast ds_read_b128
            float dx = qx - s.x;
            float dy = qy - s.y;
            float dz = qz - s.z;
            float d  = dx * dx;
            d = fmaf(dy, dy, d);
            d = fmaf(dz, dz, d);
            if (d < knnd[KNN-1]) {            // rare (~0.13%/lane)
                float cd = d;
                int   ci = t * TILE + j;
#pragma unroll
                for (int u = 0; u < KNN; ++u) {
                    bool lt = cd < knnd[u];   // strict: stable, lower-index-first
                    float td = knnd[u]; int ti = knni[u];
                    if (lt) { knnd[u] = cd; knni[u] = ci; cd = td; ci = ti; }
                }
            }
        }
    }

    // ---- KPConv influence sums: acc[p] = sum_k max(0, 1 - |rel_k - kern_p|/sigma)
    const float sigma     = 2.1f * 0.05f;
    const float inv_sigma = 1.0f / sigma;
    float acc[PK];
#pragma unroll
    for (int p = 0; p < PK; ++p) acc[p] = 0.f;

#pragma unroll 1
    for (int u = 0; u < KNN; ++u) {
        int j = knni[u];
        float rx = pts[j*3+0] - qx;
        float ry = pts[j*3+1] - qy;
        float rz = pts[j*3+2] - qz;
#pragma unroll
        for (int p = 0; p < PK; ++p) {
            float dx = rx - kpt[p].x;
            float dy = ry - kpt[p].y;
            float dz = rz - kpt[p].z;
            float d2 = dx * dx;
            d2 = fmaf(dy, dy, d2);
            d2 = fmaf(dz, dz, d2);
            float dd = sqrtf(d2);
            acc[p] += fmaxf(0.f, 1.f - dd * inv_sigma);
        }
    }

    // ---- voxel id (match jax: fp32 division by 0.1f, then floor)
    int gx = (int)floorf(qx / 0.1f);
    int gy = (int)floorf(qy / 0.1f);
    int gz = (int)floorf(qz / 0.1f);
    gx = min(max(gx, 0), GRIDB - 1);
    gy = min(max(gy, 0), GRIDB - 1);
    gz = min(max(gz, 0), GRIDB - 1);
    const int seg = (gx * GRIDB + gy) * GRIDB + gz;

    float* counts = ws;
    float* spt    = ws + NSEG;
    float* sinf   = ws + NSEG * 4;

    atomicAdd(&counts[seg], 1.0f);
    atomicAdd(&spt[seg*3+0], qx);
    atomicAdd(&spt[seg*3+1], qy);
    atomicAdd(&spt[seg*3+2], qz);
#pragma unroll
    for (int p = 0; p < PK; ++p) atomicAdd(&sinf[seg*PK + p], acc[p]);
}

// out[0 .. NSEG*3)            : points3
// out[NSEG*3 .. NSEG*3+NSEG*64): features3 = (pooled_infl @ W) / count
__global__ __launch_bounds__(64) void finalize(
    const float* __restrict__ ws,
    const float* __restrict__ W,     // [PK][1][NCOUT]
    float* __restrict__ out)
{
    const int s = blockIdx.x;
    const int d = threadIdx.x;
    __shared__ float sInfl[PK];
    if (d < PK) sInfl[d] = ws[NSEG*4 + s*PK + d];
    __syncthreads();

    float c = fmaxf(ws[s], 1.0f);
    float inv = 1.0f / c;

    float a = 0.f;
#pragma unroll
    for (int p = 0; p < PK; ++p) a = fmaf(sInfl[p], W[p*NCOUT + d], a);
    out[NSEG*3 + s*NCOUT + d] = a * inv;

    if (d < 3) out[s*3 + d] = ws[NSEG + s*3 + d] * inv;
}

extern "C" void kernel_launch(void* const* d_in, const int* in_sizes, int n_in,
                              void* d_out, int out_size, void* d_ws, size_t ws_size,
                              hipStream_t stream)
{
    const float* pts  = (const float*)d_in[0];   // points1 [65536,3]
    const float* kern = (const float*)d_in[1];   // kernel  [25,3]
    const float* W    = (const float*)d_in[2];   // W       [25,1,64]
    float* out = (float*)d_out;
    float* ws  = (float*)d_ws;

    hipMemsetAsync(ws, 0, WS_FLOATS * sizeof(float), stream);
    knn_kpconv_pool<<<NPTS / 256, 256, 0, stream>>>(pts, kern, ws);
    finalize<<<NSEG, 64, 0, stream>>>(ws, W, out);
}

// Round 2
// 378.395 us; speedup vs baseline: 16.3322x; 16.3322x over previous
//
#include <hip/hip_runtime.h>
#include <math.h>

#define NPTS  65536
#define KNN   10
#define PK    25
#define NCOUT 64
#define GRIDB 10          // pooling grid (cell 0.1) — must match reference
#define NSEG  1000
#define GRIDC 20          // kNN search grid (cell 0.05)
#define NCELL (GRIDC*GRIDC*GRIDC)
#define CELLK 0.05f

// ---- workspace layout (bytes) ----
// [0, 1048576)            : sorted float4 points          (65536 * 16)
// [1048576, +32000)       : hist   [8000] int
// [1080576, +32004)       : cstart [8001] int  (exclusive prefix, +total)
// [1112580, +32000)       : cursor [8000] int
// [1144592, +116000)      : pool floats: counts[1000] | spt[1000*3] | sinf[1000*25]
#define OFF_SORTED  0
#define OFF_HIST    1048576
#define OFF_CSTART  1080576
#define OFF_CURSOR  1112580
#define OFF_POOL    1144592

__device__ __forceinline__ int cell_of(float px, float py, float pz) {
    int gx = min((int)(px * (float)GRIDC), GRIDC - 1);
    int gy = min((int)(py * (float)GRIDC), GRIDC - 1);
    int gz = min((int)(pz * (float)GRIDC), GRIDC - 1);
    return (gx * GRIDC + gy) * GRIDC + gz;
}

__global__ __launch_bounds__(256) void hist_kernel(
    const float* __restrict__ pts, int* __restrict__ hist)
{
    int g = blockIdx.x * 256 + threadIdx.x;
    float px = pts[g*3+0], py = pts[g*3+1], pz = pts[g*3+2];
    atomicAdd(&hist[cell_of(px, py, pz)], 1);
}

__global__ __launch_bounds__(256) void scan_kernel(
    const int* __restrict__ hist, int* __restrict__ cstart, int* __restrict__ cursor)
{
    __shared__ int part[256];
    const int t = threadIdx.x;
    const int base = t * 32;                       // 256*32 = 8192 >= 8000
    int s = 0;
    for (int i = 0; i < 32; ++i) {
        int c = base + i;
        s += (c < NCELL) ? hist[c] : 0;
    }
    part[t] = s;
    __syncthreads();
    for (int off = 1; off < 256; off <<= 1) {      // Hillis-Steele inclusive
        int v = (t >= off) ? part[t - off] : 0;
        __syncthreads();
        part[t] += v;
        __syncthreads();
    }
    int run = (t == 0) ? 0 : part[t - 1];          // exclusive prefix of chunk
    for (int i = 0; i < 32; ++i) {
        int c = base + i;
        if (c < NCELL) {
            cstart[c] = run;
            cursor[c] = run;
            run += hist[c];
        }
    }
    if (t == 255) cstart[NCELL] = run;             // == NPTS
}

__global__ __launch_bounds__(256) void scatter_kernel(
    const float* __restrict__ pts, int* __restrict__ cursor, float4* __restrict__ sorted)
{
    int g = blockIdx.x * 256 + threadIdx.x;
    float px = pts[g*3+0], py = pts[g*3+1], pz = pts[g*3+2];
    int c = cell_of(px, py, pz);
    int pos = atomicAdd(&cursor[c], 1);
    sorted[pos] = make_float4(px, py, pz, 0.f);
}

__global__ __launch_bounds__(256) void knn_kpconv_pool(
    const float4* __restrict__ sorted,
    const int*    __restrict__ cstart,
    const float*  __restrict__ kern,
    float*        __restrict__ pool)
{
    __shared__ float4 kpt[PK];
    const int tid = threadIdx.x;
    const int g   = blockIdx.x * 256 + tid;
    if (tid < PK)
        kpt[tid] = make_float4(kern[tid*3+0], kern[tid*3+1], kern[tid*3+2], 0.f);
    __syncthreads();

    const float4 q = sorted[g];
    const float qx = q.x, qy = q.y, qz = q.z;
    const int cx = min((int)(qx * (float)GRIDC), GRIDC - 1);
    const int cy = min((int)(qy * (float)GRIDC), GRIDC - 1);
    const int cz = min((int)(qz * (float)GRIDC), GRIDC - 1);

    float knnd[KNN];
    int   knni[KNN];
#pragma unroll
    for (int u = 0; u < KNN; ++u) { knnd[u] = 3.4e38f; knni[u] = 0; }

    auto scanCell = [&](int x, int y, int z) {
        int c = (x * GRIDC + y) * GRIDC + z;
        int b = cstart[c], e = cstart[c + 1];
        for (int j = b; j < e; ++j) {
            float4 s = sorted[j];
            float dx = qx - s.x, dy = qy - s.y, dz = qz - s.z;
            float d = dx * dx;
            d = fmaf(dy, dy, d);
            d = fmaf(dz, dz, d);
            if (d < knnd[KNN-1]) {
                float cd = d; int ci = j;
#pragma unroll
                for (int u = 0; u < KNN; ++u) {
                    bool lt = cd < knnd[u];
                    float td = knnd[u]; int ti = knni[u];
                    if (lt) { knnd[u] = cd; knni[u] = ci; cd = td; ci = ti; }
                }
            }
        }
    };

    // ring 0..1: the 3^3 block (exact if d10 <= (1*CELLK)^2)
    {
        int xlo = max(cx-1,0), xhi = min(cx+1,GRIDC-1);
        int ylo = max(cy-1,0), yhi = min(cy+1,GRIDC-1);
        int zlo = max(cz-1,0), zhi = min(cz+1,GRIDC-1);
        for (int x = xlo; x <= xhi; ++x)
            for (int y = ylo; y <= yhi; ++y)
                for (int z = zlo; z <= zhi; ++z)
                    scanCell(x, y, z);
    }
    int ring = 1;
    while (ring < GRIDC && knnd[KNN-1] > (ring*CELLK)*(ring*CELLK)) {
        ++ring;   // scan the new Chebyshev shell only
        int xlo = max(cx-ring,0), xhi = min(cx+ring,GRIDC-1);
        int ylo = max(cy-ring,0), yhi = min(cy+ring,GRIDC-1);
        int zlo = max(cz-ring,0), zhi = min(cz+ring,GRIDC-1);
        for (int x = xlo; x <= xhi; ++x)
            for (int y = ylo; y <= yhi; ++y)
                for (int z = zlo; z <= zhi; ++z) {
                    int ax = abs(x-cx), ay = abs(y-cy), az = abs(z-cz);
                    int ch = max(ax, max(ay, az));
                    if (ch == ring) scanCell(x, y, z);
                }
    }

    // ---- KPConv influence sums: acc[p] = sum_k max(0, 1 - |rel_k - kern_p|/sigma)
    const float inv_sigma = 1.0f / (2.1f * 0.05f);
    float acc[PK];
#pragma unroll
    for (int p = 0; p < PK; ++p) acc[p] = 0.f;

#pragma unroll 1
    for (int u = 0; u < KNN; ++u) {
        float4 s = sorted[knni[u]];
        float rx = s.x - qx, ry = s.y - qy, rz = s.z - qz;
#pragma unroll
        for (int p = 0; p < PK; ++p) {
            float dx = rx - kpt[p].x, dy = ry - kpt[p].y, dz = rz - kpt[p].z;
            float d2 = dx * dx;
            d2 = fmaf(dy, dy, d2);
            d2 = fmaf(dz, dz, d2);
            acc[p] += fmaxf(0.f, 1.f - sqrtf(d2) * inv_sigma);
        }
    }

    // ---- pooling voxel id (match jax: fp32 division by 0.1f, floor)
    int gx = (int)floorf(qx / 0.1f);
    int gy = (int)floorf(qy / 0.1f);
    int gz = (int)floorf(qz / 0.1f);
    gx = min(max(gx, 0), GRIDB - 1);
    gy = min(max(gy, 0), GRIDB - 1);
    gz = min(max(gz, 0), GRIDB - 1);
    const int seg = (gx * GRIDB + gy) * GRIDB + gz;

    float* counts = pool;
    float* spt    = pool + NSEG;
    float* sinf   = pool + NSEG * 4;
    atomicAdd(&counts[seg], 1.0f);
    atomicAdd(&spt[seg*3+0], qx);
    atomicAdd(&spt[seg*3+1], qy);
    atomicAdd(&spt[seg*3+2], qz);
#pragma unroll
    for (int p = 0; p < PK; ++p) atomicAdd(&sinf[seg*PK + p], acc[p]);
}

// out[0 .. NSEG*3)             : points3
// out[NSEG*3 .. NSEG*3+NSEG*64): features3 = (pooled_infl @ W) / count
__global__ __launch_bounds__(64) void finalize(
    const float* __restrict__ pool,
    const float* __restrict__ W,
    float* __restrict__ out)
{
    const int s = blockIdx.x;
    const int d = threadIdx.x;
    __shared__ float sInfl[PK];
    if (d < PK) sInfl[d] = pool[NSEG*4 + s*PK + d];
    __syncthreads();

    float c = fmaxf(pool[s], 1.0f);
    float inv = 1.0f / c;

    float a = 0.f;
#pragma unroll
    for (int p = 0; p < PK; ++p) a = fmaf(sInfl[p], W[p*NCOUT + d], a);
    out[NSEG*3 + s*NCOUT + d] = a * inv;

    if (d < 3) out[s*3 + d] = pool[NSEG + s*3 + d] * inv;
}

extern "C" void kernel_launch(void* const* d_in, const int* in_sizes, int n_in,
                              void* d_out, int out_size, void* d_ws, size_t ws_size,
                              hipStream_t stream)
{
    const float* pts  = (const float*)d_in[0];
    const float* kern = (const float*)d_in[1];
    const float* W    = (const float*)d_in[2];
    float* out = (float*)d_out;
    char*  ws  = (char*)d_ws;

    float4* sorted = (float4*)(ws + OFF_SORTED);
    int*    hist   = (int*)   (ws + OFF_HIST);
    int*    cstart = (int*)   (ws + OFF_CSTART);
    int*    cursor = (int*)   (ws + OFF_CURSOR);
    float*  pool   = (float*) (ws + OFF_POOL);

    hipMemsetAsync(hist, 0, NCELL * sizeof(int), stream);
    hipMemsetAsync(pool, 0, NSEG * (1 + 3 + PK) * sizeof(float), stream);

    hist_kernel   <<<NPTS/256, 256, 0, stream>>>(pts, hist);
    scan_kernel   <<<1,        256, 0, stream>>>(hist, cstart, cursor);
    scatter_kernel<<<NPTS/256, 256, 0, stream>>>(pts, cursor, sorted);
    knn_kpconv_pool<<<NPTS/256, 256, 0, stream>>>(sorted, cstart, kern, pool);
    finalize      <<<NSEG, 64, 0, stream>>>(pool, W, out);
}